// Round 1
// baseline (1521.552 us; speedup 1.0000x reference)
//
#include <hip/hip_runtime.h>
#include <cstdint>

#define DIVUP(a,b) (((a)+(b)-1)/(b))

__device__ __forceinline__ float cubicw(float x) {
  // PyTorch bicubic kernel, a = -0.75
  float ax = fabsf(x);
  float ax2 = ax * ax;
  float ax3 = ax2 * ax;
  if (ax <= 1.0f) return 1.25f * ax3 - 2.25f * ax2 + 1.0f;
  if (ax < 2.0f)  return -0.75f * ax3 + 3.75f * ax2 - 6.0f * ax + 3.0f;
  return 0.0f;
}

// S[b,pix] = sum_c x[b,c,pix]^2
__global__ void sumsq_kernel(const float* __restrict__ x, float* __restrict__ S,
                             int C, int HW, int total) {
  int i = blockIdx.x * blockDim.x + threadIdx.x;
  if (i >= total) return;
  int pix = i % HW, b = i / HW;
  const float* p = x + (size_t)b * C * HW + pix;
  float s = 0.f;
  for (int c = 0; c < C; ++c) { float v = p[(size_t)c * HW]; s += v * v; }
  S[i] = s;
}

// invn[b,p] = 1 / max(sqrt(3x3 zero-padded window sum of S), 1e-12)
__global__ void invnorm_kernel(const float* __restrict__ S, float* __restrict__ invn,
                               int H, int W, int total) {
  int i = blockIdx.x * blockDim.x + threadIdx.x;
  if (i >= total) return;
  int p = i % (H * W), b = i / (H * W);
  int ph = p / W, pw = p % W;
  const float* Sb = S + (size_t)b * H * W;
  float s = 0.f;
  for (int ki = 0; ki < 3; ++ki) {
    int y = ph + ki - 1;
    if (y < 0 || y >= H) continue;
    for (int kj = 0; kj < 3; ++kj) {
      int xx = pw + kj - 1;
      if (xx < 0 || xx >= W) continue;
      s += Sb[y * W + xx];
    }
  }
  float n = fmaxf(sqrtf(s), 1e-12f);
  invn[i] = 1.0f / n;
}

// l-layout descriptors: out[b][d][p] = unfold(x)[d,p] * invn[b,p]   (D-major)
__global__ void desc_l_kernel(const float* __restrict__ x, const float* __restrict__ invn,
                              float* __restrict__ out, int C, int H, int W, int total) {
  int i = blockIdx.x * blockDim.x + threadIdx.x;
  if (i >= total) return;
  int HW = H * W, D = C * 9;
  int p = i % HW;
  int d = (i / HW) % D;
  int b = i / (HW * D);
  int c = d / 9, r = d % 9, ki = r / 3, kj = r % 3;
  int ph = p / W, pw = p % W;
  int y = ph + ki - 1, xx = pw + kj - 1;
  float v = 0.f;
  if (y >= 0 && y < H && xx >= 0 && xx < W) v = x[((size_t)(b * C + c) * H + y) * W + xx];
  out[i] = v * invn[b * HW + p];
}

// r-layout descriptors: out[b][p][d]  (N-major rows of length D)
__global__ void desc_r_kernel(const float* __restrict__ x, const float* __restrict__ invn,
                              float* __restrict__ out, int C, int H, int W, int total) {
  int i = blockIdx.x * blockDim.x + threadIdx.x;
  if (i >= total) return;
  int HW = H * W, D = C * 9;
  int d = i % D;
  int p = (i / D) % HW;
  int b = i / (D * HW);
  int c = d / 9, r = d % 9, ki = r / 3, kj = r % 3;
  int ph = p / W, pw = p % W;
  int y = ph + ki - 1, xx = pw + kj - 1;
  float v = 0.f;
  if (y >= 0 && y < H && xx >= 0 && xx < W) v = x[((size_t)(b * C + c) * H + y) * W + xx];
  out[i] = v * invn[b * HW + p];
}

// Axis-1 bicubic upsample to 4096 rows: out[b][n][j] = sum_t w[t]*Rin[b][clip(idx)][j]
__global__ void upsample_n_kernel(const float* __restrict__ Rin, float* __restrict__ out,
                                  int Nin, int cols, float invscale, int total) {
  int i = blockIdx.x * blockDim.x + threadIdx.x;
  if (i >= total) return;
  int j = i % cols;
  int n = (i / cols) & 4095;
  int b = i / (cols * 4096);
  float src = (n + 0.5f) * invscale - 0.5f;
  float f = floorf(src);
  float tt = src - f;
  int fi = (int)f;
  const float* Rb = Rin + (size_t)b * Nin * cols;
  float s = 0.f;
#pragma unroll
  for (int tp = 0; tp < 4; ++tp) {
    int ii = min(max(fi + tp - 1, 0), Nin - 1);
    s += cubicw(tt - (float)(tp - 1)) * Rb[(size_t)ii * cols + j];
  }
  out[i] = s;
}

__global__ void init_packed_kernel(unsigned long long* __restrict__ p, int n) {
  int i = blockIdx.x * blockDim.x + threadIdx.x;
  if (i < n) p[i] = 0ull;
}

// Tiled fp32 GEMM: C[M,N] = A[M,K] * B[K,N], row-major, batched over gridDim.z.
// FUSED variant (M=N=4096): adds axis-2 bicubic taps of up2/up1, /3, then
// packed max/argmax over rows into `packed` (one atomicMax per column/block).
template<bool FUSED>
__global__ __launch_bounds__(256)
void gemm_kernel(const float* __restrict__ A, const float* __restrict__ B,
                 float* __restrict__ C, int M, int N, int K,
                 const float* __restrict__ up2, const float* __restrict__ up1,
                 unsigned long long* __restrict__ packed) {
  int b = blockIdx.z;
  const float* Ab = A + (size_t)b * M * K;
  const float* Bb = B + (size_t)b * K * N;
  __shared__ float As[16][68];   // [k][row], padded to break write conflicts
  __shared__ float Bs[16][64];   // [k][col]
  int row0 = blockIdx.y * 64;
  int col0 = blockIdx.x * 64;
  int t = threadIdx.x;
  int tx = t & 15, ty = t >> 4;
  float acc[4][4] = {};
  int la_r = t >> 2;            // 0..63 (A row within tile)
  int la_k = (t & 3) << 2;      // 0,4,8,12
  int lb_r = t >> 4;            // 0..15 (B k-row)
  int lb_c = (t & 15) << 2;     // 0..60
  const float* Aptr = Ab + (size_t)(row0 + la_r) * K + la_k;
  const float* Bptr = Bb + (size_t)lb_r * N + col0 + lb_c;
  for (int k0 = 0; k0 < K; k0 += 16) {
    float4 av = *(const float4*)(Aptr + k0);
    float4 bv = *(const float4*)(Bptr + (size_t)k0 * N);
    __syncthreads();
    As[la_k + 0][la_r] = av.x;
    As[la_k + 1][la_r] = av.y;
    As[la_k + 2][la_r] = av.z;
    As[la_k + 3][la_r] = av.w;
    *(float4*)&Bs[lb_r][lb_c] = bv;
    __syncthreads();
#pragma unroll
    for (int k = 0; k < 16; ++k) {
      float4 a = *(const float4*)&As[k][ty << 2];
      float4 bq = *(const float4*)&Bs[k][tx << 2];
      float av4[4] = {a.x, a.y, a.z, a.w};
      float bv4[4] = {bq.x, bq.y, bq.z, bq.w};
#pragma unroll
      for (int ii = 0; ii < 4; ++ii)
#pragma unroll
        for (int jj = 0; jj < 4; ++jj)
          acc[ii][jj] = fmaf(av4[ii], bv4[jj], acc[ii][jj]);
    }
  }

  if constexpr (!FUSED) {
    float* Cb = C + (size_t)b * M * N;
#pragma unroll
    for (int ii = 0; ii < 4; ++ii) {
      float4 v = make_float4(acc[ii][0], acc[ii][1], acc[ii][2], acc[ii][3]);
      *(float4*)&Cb[(size_t)(row0 + (ty << 2) + ii) * N + col0 + (tx << 2)] = v;
    }
  } else {
    __shared__ unsigned long long red[16][64];
#pragma unroll
    for (int jj = 0; jj < 4; ++jj) {
      int gm = col0 + (tx << 2) + jj;
      // scale-4 taps into up2 columns (width 1024)
      float src2 = (gm + 0.5f) * 0.25f - 0.5f;
      float f2 = floorf(src2); float t2 = src2 - f2; int i2 = (int)f2;
      int idx2[4]; float w2[4];
#pragma unroll
      for (int tp = 0; tp < 4; ++tp) {
        idx2[tp] = min(max(i2 + tp - 1, 0), 1023);
        w2[tp] = cubicw(t2 - (float)(tp - 1));
      }
      // scale-16 taps into up1 columns (width 256)
      float src1 = (gm + 0.5f) * 0.0625f - 0.5f;
      float f1 = floorf(src1); float t1 = src1 - f1; int i1 = (int)f1;
      int idx1[4]; float w1[4];
#pragma unroll
      for (int tp = 0; tp < 4; ++tp) {
        idx1[tp] = min(max(i1 + tp - 1, 0), 255);
        w1[tp] = cubicw(t1 - (float)(tp - 1));
      }
      unsigned long long best = 0ull;
#pragma unroll
      for (int ii = 0; ii < 4; ++ii) {
        int gn = row0 + (ty << 2) + ii;
        const float* r2row = up2 + ((size_t)b * 4096 + gn) * 1024;
        const float* r1row = up1 + ((size_t)b * 4096 + gn) * 256;
        float v = acc[ii][jj];
        v += w2[0] * r2row[idx2[0]] + w2[1] * r2row[idx2[1]]
           + w2[2] * r2row[idx2[2]] + w2[3] * r2row[idx2[3]];
        v += w1[0] * r1row[idx1[0]] + w1[1] * r1row[idx1[1]]
           + w1[2] * r1row[idx1[2]] + w1[3] * r1row[idx1[3]];
        v *= (1.0f / 3.0f);
        unsigned int fb = __float_as_uint(v);
        unsigned int key = (fb & 0x80000000u) ? ~fb : (fb | 0x80000000u);
        unsigned long long pk = ((unsigned long long)key << 32)
                              | (unsigned long long)(0xFFFFFFFFu - (unsigned)gn);
        best = best > pk ? best : pk;
      }
      red[ty][(tx << 2) + jj] = best;
    }
    __syncthreads();
    if (t < 64) {
      unsigned long long bb = red[0][t];
#pragma unroll
      for (int r = 1; r < 16; ++r) bb = bb > red[r][t] ? bb : red[r][t];
      atomicMax(&packed[(size_t)b * 4096 + col0 + t], bb);
    }
  }
}

__global__ void finalize_kernel(const unsigned long long* __restrict__ packed,
                                float* __restrict__ s3_out, int* __restrict__ arg, int total) {
  int i = blockIdx.x * blockDim.x + threadIdx.x;
  if (i >= total) return;
  unsigned long long pk = packed[i];
  unsigned int key = (unsigned int)(pk >> 32);
  unsigned int fb = (key & 0x80000000u) ? (key ^ 0x80000000u) : ~key;
  s3_out[i] = __uint_as_float(fb);
  arg[i] = (int)(0xFFFFFFFFu - (unsigned int)(pk & 0xFFFFFFFFull));
}

// fold(gather(unfold(ref, KK,PP,SS), arg)) / 9 — pure gather, <=9 taps/output.
template<int KK, int SS, int PP>
__global__ void fold_gather_kernel(const float* __restrict__ ref, const int* __restrict__ arg,
                                   float* __restrict__ out, int C, int H, int W, int total) {
  int i = blockIdx.x * blockDim.x + threadIdx.x;
  if (i >= total) return;
  int w = i % W;
  int h = (i / W) % H;
  int c = (i / (W * H)) % C;
  int b = i / (W * H * C);
  int y = h + PP, x = w + PP;
  int ho_lo = (y - KK + 1) > 0 ? (y - KK + 1 + SS - 1) / SS : 0;
  int ho_hi = min(63, y / SS);
  int wo_lo = (x - KK + 1) > 0 ? (x - KK + 1 + SS - 1) / SS : 0;
  int wo_hi = min(63, x / SS);
  const int* argb = arg + b * 4096;
  const float* refb = ref + (size_t)(b * C + c) * H * W;
  float acc = 0.f;
  for (int ho = ho_lo; ho <= ho_hi; ++ho) {
    int ki = y - SS * ho;
    for (int wo = wo_lo; wo <= wo_hi; ++wo) {
      int kj = x - SS * wo;
      int q = argb[(ho << 6) + wo];
      int qh = q >> 6, qw = q & 63;
      int ry = SS * qh + ki - PP;
      int rx = SS * qw + kj - PP;
      if (ry >= 0 && ry < H && rx >= 0 && rx < W) acc += refb[ry * W + rx];
    }
  }
  out[i] = acc * (1.0f / 9.0f);
}

extern "C" void kernel_launch(void* const* d_in, const int* in_sizes, int n_in,
                              void* d_out, int out_size, void* d_ws, size_t ws_size,
                              hipStream_t stream) {
  const float* lrsr1 = (const float*)d_in[0];
  const float* lrsr2 = (const float*)d_in[1];
  const float* lrsr3 = (const float*)d_in[2];
  const float* refsr1 = (const float*)d_in[3];
  const float* refsr2 = (const float*)d_in[4];
  const float* refsr3 = (const float*)d_in[5];
  const float* ref1 = (const float*)d_in[6];
  const float* ref2 = (const float*)d_in[7];
  const float* ref3 = (const float*)d_in[8];
  float* out = (float*)d_out;
  float* ws = (float*)d_ws;

  const int B = 2;
  // workspace layout (floats) — ~112 MB total
  size_t off_r3n = 0;                                   // [2,4096,576]
  size_t off_l3n = off_r3n + (size_t)B * 4096 * 576;    // [2,576,4096]
  size_t off_r2n = off_l3n + (size_t)B * 576 * 4096;    // [2,1024,1152]
  size_t off_l2n = off_r2n + (size_t)B * 1024 * 1152;   // [2,1152,1024]
  size_t off_r1n = off_l2n + (size_t)B * 1152 * 1024;   // [2,256,2304]
  size_t off_l1n = off_r1n + (size_t)B * 256 * 2304;    // [2,2304,256]
  size_t off_R2  = off_l1n + (size_t)B * 2304 * 256;    // [2,1024,1024]
  size_t off_R1  = off_R2  + (size_t)B * 1024 * 1024;   // [2,256,256]
  size_t off_up2 = off_R1  + (size_t)B * 256 * 256;     // [2,4096,1024]
  size_t off_up1 = off_up2 + (size_t)B * 4096 * 1024;   // [2,4096,256]
  size_t off_S   = off_up1 + (size_t)B * 4096 * 256;    // [2,4096] (reused)
  size_t off_invn= off_S   + (size_t)B * 4096;          // [2,4096] (reused)
  size_t off_pk  = off_invn+ (size_t)B * 4096;          // [2,4096] u64 (=2 floats each)
  size_t off_arg = off_pk  + (size_t)B * 4096 * 2;      // [2,4096] int

  auto run_desc = [&](const float* x, int C, int H, int W, float* outbuf, bool r_layout) {
    int HW = H * W;
    int tS = B * HW;
    sumsq_kernel<<<DIVUP(tS, 256), 256, 0, stream>>>(x, ws + off_S, C, HW, tS);
    invnorm_kernel<<<DIVUP(tS, 256), 256, 0, stream>>>(ws + off_S, ws + off_invn, H, W, tS);
    int tD = B * C * 9 * HW;
    if (r_layout)
      desc_r_kernel<<<DIVUP(tD, 256), 256, 0, stream>>>(x, ws + off_invn, outbuf, C, H, W, tD);
    else
      desc_l_kernel<<<DIVUP(tD, 256), 256, 0, stream>>>(x, ws + off_invn, outbuf, C, H, W, tD);
  };

  run_desc(lrsr3, 64, 64, 64, ws + off_l3n, false);
  run_desc(refsr3, 64, 64, 64, ws + off_r3n, true);
  run_desc(lrsr2, 128, 32, 32, ws + off_l2n, false);
  run_desc(refsr2, 128, 32, 32, ws + off_r2n, true);
  run_desc(lrsr1, 256, 16, 16, ws + off_l1n, false);
  run_desc(refsr1, 256, 16, 16, ws + off_r1n, true);

  // small correlation GEMMs R2, R1
  {
    dim3 g(1024 / 64, 1024 / 64, B);
    gemm_kernel<false><<<g, 256, 0, stream>>>(ws + off_r2n, ws + off_l2n, ws + off_R2,
                                              1024, 1024, 1152, nullptr, nullptr, nullptr);
  }
  {
    dim3 g(256 / 64, 256 / 64, B);
    gemm_kernel<false><<<g, 256, 0, stream>>>(ws + off_r1n, ws + off_l1n, ws + off_R1,
                                              256, 256, 2304, nullptr, nullptr, nullptr);
  }

  // axis-1 bicubic upsample of R2 (x4) and R1 (x16) to 4096 rows
  {
    int tU2 = B * 4096 * 1024;
    upsample_n_kernel<<<DIVUP(tU2, 256), 256, 0, stream>>>(ws + off_R2, ws + off_up2,
                                                           1024, 1024, 0.25f, tU2);
    int tU1 = B * 4096 * 256;
    upsample_n_kernel<<<DIVUP(tU1, 256), 256, 0, stream>>>(ws + off_R1, ws + off_up1,
                                                           256, 256, 0.0625f, tU1);
  }

  unsigned long long* pk = (unsigned long long*)(ws + off_pk);
  init_packed_kernel<<<DIVUP(B * 4096, 256), 256, 0, stream>>>(pk, B * 4096);

  // fused R3 GEMM + bicubic add + max/argmax
  {
    dim3 g(4096 / 64, 4096 / 64, B);
    gemm_kernel<true><<<g, 256, 0, stream>>>(ws + off_r3n, ws + off_l3n, nullptr,
                                             4096, 4096, 576,
                                             ws + off_up2, ws + off_up1, pk);
  }

  int* argp = (int*)(ws + off_arg);
  finalize_kernel<<<DIVUP(B * 4096, 256), 256, 0, stream>>>(pk, out, argp, B * 4096);

  // transfer: fold(gather(unfold(ref_lvX)))/9
  float* T3 = out + 8192;
  float* T2 = T3 + (size_t)B * 256 * 64 * 64;
  float* T1 = T2 + (size_t)B * 128 * 128 * 128;
  {
    int tt = B * 256 * 64 * 64;
    fold_gather_kernel<3, 1, 1><<<DIVUP(tt, 256), 256, 0, stream>>>(ref3, argp, T3, 256, 64, 64, tt);
  }
  {
    int tt = B * 128 * 128 * 128;
    fold_gather_kernel<6, 2, 2><<<DIVUP(tt, 256), 256, 0, stream>>>(ref2, argp, T2, 128, 128, 128, tt);
  }
  {
    int tt = B * 64 * 256 * 256;
    fold_gather_kernel<12, 4, 4><<<DIVUP(tt, 256), 256, 0, stream>>>(ref1, argp, T1, 64, 256, 256, tt);
  }
}